// Round 5
// baseline (85.601 us; speedup 1.0000x reference)
//
#include <hip/hip_runtime.h>
#include <stdint.h>

#define H_ 384
#define W_ 512
#define HW_ (H_ * W_)
#define NIMG 32
#define EPSF 1e-6f
#define HBLK 16            // hist blocks per image
#define HTHR 512           // threads per hist block
#define PXB (HW_ / HBLK)   // 12288 px per hist block
#define CITER (PXB / (HTHR * 4))  // 6
#define NPARTS (192 * 32)
#define SENT 0xFFFFFFFFu

typedef float v2f __attribute__((ext_vector_type(2)));

// ---- workspace layout (u32 indices). NOTHING is pre-zeroed: every buffer ----
// ---- is fully overwritten before being read, every call.                ----
#define OFF_MSUM   0                       // 32 i32  (hist1 publishes)
#define OFF_FCNT   32                      // 32 i32  (hist1 publishes)
#define OFF_KREM1  64                      // 32 i32  (hist1 -> hist2)
#define OFF_KREM2  96                      // 32 i32  (hist2 -> sel0)
#define OFF_PREF1  128                     // 32 u32  (hist1 -> hist2)
#define OFF_PREF2  160                     // 32 u32  (hist2 -> sel0)
#define OFF_SCALE  192                     // 32 f32  (sel0 -> main)
#define OFF_POSE   224                     // 32 f32  (sel0 -> finalize)
#define OFF_PMF    256                     // 32*16*2 i32 = 1024
#define OFF_PART   1280                    // 6144*5 f32 = 30720
#define OFF_PHA    32000                   // 32*16*2048 u32 (hist0 & hist2 partials)
#define OFF_PHB    (OFF_PHA + NIMG*HBLK*2048)   // 32*16*2048 u32 (hist1 partials)
#define OFF_KEYS   (OFF_PHB + NIMG*HBLK*2048)   // 32*HW u32
#define WS_KEYS_NEED ((unsigned long long)(OFF_KEYS + (size_t)NIMG * HW_) * 4ull)

__device__ __forceinline__ bool finitef(float x) {
    return ((__float_as_uint(x) >> 23) & 0xFFu) != 0xFFu;
}
__device__ __forceinline__ v2f vsel(bool a, bool b, v2f v) {
    v2f r; r.x = a ? v.x : 0.0f; r.y = b ? v.y : 0.0f; return r;
}

// ---------------- pass 1: keys + partial hist of bits[31:21] (ballot-dedup) ----------------
__global__ __launch_bounds__(HTHR) void hist0_k(
    const float* __restrict__ dp, const float* __restrict__ dg,
    const uint8_t* __restrict__ vmask, uint32_t* __restrict__ keys,
    uint32_t* __restrict__ ws, int write_keys)
{
    __shared__ uint32_t lh[2048];
    __shared__ int sm[8], sf[8];
    const int img = blockIdx.y, blk = blockIdx.x, t = threadIdx.x;
    for (int b = t; b < 2048; b += HTHR) lh[b] = 0;
    __syncthreads();

    const size_t base = (size_t)img * HW_;
    const float* dpi = dp + base;
    const float* dgi = dg + base;
    const uint8_t* mi = vmask + base;
    uint32_t* ki = keys + base;

    int m2c = 0, fmc = 0;

    for (int c = 0; c < CITER; ++c) {
        const int pix = blk * PXB + c * (HTHR * 4) + t * 4;
        const float4 v_dp = *reinterpret_cast<const float4*>(dpi + pix);
        const float4 v_dg = *reinterpret_cast<const float4*>(dgi + pix);
        const uchar4 v_m  = *reinterpret_cast<const uchar4*>(mi + pix);
        const float dpa[4] = {v_dp.x, v_dp.y, v_dp.z, v_dp.w};
        const float dga[4] = {v_dg.x, v_dg.y, v_dg.z, v_dg.w};
        const uint8_t ma[4] = {v_m.x, v_m.y, v_m.z, v_m.w};
        uint32_t kout[4]; int bins[4]; bool fms[4];
#pragma unroll
        for (int e = 0; e < 4; ++e) {
            const float dgv = dga[e], dpv = dpa[e];
            const bool vm = ma[e] && finitef(dgv) && (dgv > 1e-6f);
            const bool m2 = vm && finitef(dpv) && (dpv > EPSF);
            const float ratio = dpv / fmaxf(dgv, EPSF);
            const bool fm = m2 && finitef(ratio);
            m2c += (int)m2; fmc += (int)fm;
            const uint32_t key = fm ? __float_as_uint(ratio) : SENT;
            kout[e] = key;
            bins[e] = (int)(key >> 21);
            fms[e] = fm;
        }
        if (write_keys)
            *reinterpret_cast<uint4*>(ki + pix) = make_uint4(kout[0], kout[1], kout[2], kout[3]);

#pragma unroll
        for (int e = 0; e < 4; ++e) {
            const bool fm = fms[e];
            const int bin = bins[e];
            unsigned long long todo = __ballot(fm);
            while (todo) {
                const int lead = (int)__ffsll(todo) - 1;
                const int lbin = __shfl(bin, lead);
                const unsigned long long same = __ballot(fm && (bin == lbin));
                if ((t & 63) == lead)
                    atomicAdd(&lh[lbin], (uint32_t)__popcll(same));
                todo &= ~same;
            }
        }
    }

    for (int o = 32; o > 0; o >>= 1) { m2c += __shfl_down(m2c, o); fmc += __shfl_down(fmc, o); }
    if ((t & 63) == 0) { sm[t >> 6] = m2c; sf[t >> 6] = fmc; }
    __syncthreads();
    if (t == 0) {
        int M = 0, F = 0;
        for (int w = 0; w < 8; ++w) { M += sm[w]; F += sf[w]; }
        int* pmf = (int*)(ws + OFF_PMF) + (img * HBLK + blk) * 2;
        pmf[0] = M; pmf[1] = F;
    }

    uint32_t* phb = ws + OFF_PHA + (size_t)(img * HBLK + blk) * 2048;
    for (int b = t; b < 2048; b += HTHR) phb[b] = lh[b];
}

// ---------------- passes 2/3 with FUSED select prologue ----------------
// PASS==1: prologue = select bits[31:21] from PHA partials; body hists bits[20:10] -> PHB.
// PASS==2: prologue = select bits[20:10] from PHB partials; body hists bits[9:0]  -> PHA.
template<int PASS, bool USE_KEYS>
__global__ __launch_bounds__(HTHR) void histp_k(
    const float* __restrict__ dp, const float* __restrict__ dg,
    const uint8_t* __restrict__ vmask, const uint32_t* __restrict__ keys,
    uint32_t* __restrict__ ws)
{
    __shared__ uint32_t lh[2048];
    __shared__ int s_bin, s_krem, s_msum, s_fcnt;
    __shared__ uint32_t s_pref;
    const int img = blockIdx.y, blk = blockIdx.x, t = threadIdx.x;

    // ---- fused select prologue (every block computes identical result) ----
    const uint32_t* pin = ws + (PASS == 1 ? OFF_PHA : OFF_PHB) + (size_t)img * HBLK * 2048;
    uint32_t local[4];
#pragma unroll
    for (int c = 0; c < 4; ++c) local[c] = 0;
    for (int b = 0; b < HBLK; ++b) {
        const uint32_t* row = pin + b * 2048 + t * 4;
#pragma unroll
        for (int c = 0; c < 4; ++c) local[c] += row[c];
    }
    uint32_t cs = local[0] + local[1] + local[2] + local[3];
    lh[t] = cs;
    if (t == 0) {
        s_bin = 0; s_krem = 0;
        if (PASS == 1) {
            const int* pmf = (const int*)(ws + OFF_PMF) + img * HBLK * 2;
            int M = 0, F = 0;
            for (int b = 0; b < HBLK; ++b) { M += pmf[2 * b]; F += pmf[2 * b + 1]; }
            s_msum = M; s_fcnt = F;
        }
    }
    __syncthreads();
    for (int off = 1; off < HTHR; off <<= 1) {
        const uint32_t v = (t >= off) ? lh[t - off] : 0u;
        __syncthreads();
        lh[t] += v;
        __syncthreads();
    }
    const uint32_t incl = lh[t];
    const uint32_t excl = incl - cs;
    const uint32_t k = (uint32_t)((PASS == 1) ? max((s_fcnt - 1) / 2, 0)
                                              : ((const int*)(ws + OFF_KREM1))[img]);
    if (k >= excl && k < incl) {
        uint32_t cum = excl;
#pragma unroll
        for (int c = 0; c < 4; ++c) {
            if (cum + local[c] > k) { s_bin = t * 4 + c; s_krem = (int)(k - cum); break; }
            cum += local[c];
        }
    }
    __syncthreads();
    if (t == 0) {
        uint32_t np;
        if (PASS == 1) {
            np = (uint32_t)s_bin << 21;
            ((int*)(ws + OFF_MSUM))[img] = s_msum;
            ((int*)(ws + OFF_FCNT))[img] = s_fcnt;
            (ws + OFF_PREF1)[img] = np;
            ((int*)(ws + OFF_KREM1))[img] = s_krem;
        } else {
            np = (ws + OFF_PREF1)[img] | ((uint32_t)s_bin << 10);
            (ws + OFF_PREF2)[img] = np;
            ((int*)(ws + OFF_KREM2))[img] = s_krem;
        }
        s_pref = np;
    }
    __syncthreads();
    const uint32_t pref = s_pref;

    // ---- histogram body ----
    for (int b = t; b < 2048; b += HTHR) lh[b] = 0;
    __syncthreads();

    const int mshift = (PASS == 1) ? 21 : 10;
    const int bshift = (PASS == 1) ? 10 : 0;
    const uint32_t bmask = (PASS == 1) ? 2047u : 1023u;
    const uint32_t pm = pref >> mshift;
    const size_t base = (size_t)img * HW_;

    for (int c = 0; c < CITER; ++c) {
        const int pix = blk * PXB + c * (HTHR * 4) + t * 4;
        uint32_t k4[4];
        if constexpr (USE_KEYS) {
            const uint4 kv = *reinterpret_cast<const uint4*>(keys + base + pix);
            k4[0] = kv.x; k4[1] = kv.y; k4[2] = kv.z; k4[3] = kv.w;
        } else {
            const float4 v_dp = *reinterpret_cast<const float4*>(dp + base + pix);
            const float4 v_dg = *reinterpret_cast<const float4*>(dg + base + pix);
            const uchar4 v_m  = *reinterpret_cast<const uchar4*>(vmask + base + pix);
            const float dpa[4] = {v_dp.x, v_dp.y, v_dp.z, v_dp.w};
            const float dga[4] = {v_dg.x, v_dg.y, v_dg.z, v_dg.w};
            const uint8_t ma[4] = {v_m.x, v_m.y, v_m.z, v_m.w};
#pragma unroll
            for (int e = 0; e < 4; ++e) {
                const float dgv = dga[e], dpv = dpa[e];
                const bool vm = ma[e] && finitef(dgv) && (dgv > 1e-6f);
                const bool m2 = vm && finitef(dpv) && (dpv > EPSF);
                const float ratio = dpv / fmaxf(dgv, EPSF);
                const bool fm = m2 && finitef(ratio);
                k4[e] = fm ? __float_as_uint(ratio) : SENT;
            }
        }
#pragma unroll
        for (int e = 0; e < 4; ++e) {
            const uint32_t key = k4[e];
            if ((key >> mshift) == pm)
                atomicAdd(&lh[(key >> bshift) & bmask], 1u);
        }
    }
    __syncthreads();

    uint32_t* pout = ws + (PASS == 1 ? OFF_PHB : OFF_PHA) + (size_t)(img * HBLK + blk) * 2048;
    const int nb = (PASS == 1) ? 2048 : 1024;
    for (int b = t; b < nb; b += HTHR) pout[b] = lh[b];
}

// ---------------- final select (bits 9:0) + scale + pose ----------------
__global__ __launch_bounds__(256) void sel0_k(
    uint32_t* __restrict__ ws,
    const float* __restrict__ intr, const float* __restrict__ posegt,
    const float* __restrict__ posepred)
{
    const int img = blockIdx.x;
    const int t = threadIdx.x;
    const uint32_t* ph = ws + OFF_PHA + (size_t)img * HBLK * 2048;
    uint32_t local[4];
#pragma unroll
    for (int c = 0; c < 4; ++c) local[c] = 0;
    for (int b = 0; b < HBLK; ++b) {
        const uint32_t* row = ph + b * 2048 + t * 4;
#pragma unroll
        for (int c = 0; c < 4; ++c) local[c] += row[c];
    }
    uint32_t cs = local[0] + local[1] + local[2] + local[3];

    __shared__ uint32_t sscan[256];
    __shared__ int s_bin;
    sscan[t] = cs;
    if (t == 0) s_bin = 0;
    __syncthreads();
    for (int off = 1; off < 256; off <<= 1) {
        const uint32_t v = (t >= off) ? sscan[t - off] : 0u;
        __syncthreads();
        sscan[t] += v;
        __syncthreads();
    }
    const uint32_t incl = sscan[t];
    const uint32_t excl = incl - cs;
    const uint32_t k = (uint32_t)((const int*)(ws + OFF_KREM2))[img];
    if (k >= excl && k < incl) {
        uint32_t cum = excl;
#pragma unroll
        for (int c = 0; c < 4; ++c) {
            if (cum + local[c] > k) { s_bin = t * 4 + c; break; }
            cum += local[c];
        }
    }
    __syncthreads();

    if (t == 0) {
        const uint32_t med_u = (ws + OFF_PREF2)[img] | (uint32_t)s_bin;
        const float med = __uint_as_float(med_u);
        float sc_ = fminf(fmaxf(med, 0.001f), 1000.0f);
        const int fcnt = ((const int*)(ws + OFF_FCNT))[img];
        const int msum = ((const int*)(ws + OFF_MSUM))[img];
        if (msum < 16 || fcnt == 0) sc_ = 1.0f;
        ((float*)(ws + OFF_SCALE))[img] = sc_;

        const float* p = posegt + img * 16;
        const float m00 = p[0], m01 = p[1], m02 = p[2], tx = p[3];
        const float m10 = p[4], m11 = p[5], m12 = p[6], ty = p[7];
        const float m20 = p[8], m21 = p[9], m22 = p[10], tz = p[11];
        float qa[4];
        qa[0] = sqrtf(fmaxf(1.0f + m00 + m11 + m22, 0.0f));
        qa[1] = sqrtf(fmaxf(1.0f + m00 - m11 - m22, 0.0f));
        qa[2] = sqrtf(fmaxf(1.0f - m00 + m11 - m22, 0.0f));
        qa[3] = sqrtf(fmaxf(1.0f - m00 - m11 + m22, 0.0f));
        int best = 0; float bv = qa[0];
        for (int i2 = 1; i2 < 4; ++i2) if (qa[i2] > bv) { bv = qa[i2]; best = i2; }
        float c0, c1, c2, c3;
        if (best == 0)      { c0 = qa[0]*qa[0]; c1 = m21 - m12;   c2 = m02 - m20;   c3 = m10 - m01; }
        else if (best == 1) { c0 = m21 - m12;   c1 = qa[1]*qa[1]; c2 = m10 + m01;   c3 = m02 + m20; }
        else if (best == 2) { c0 = m02 - m20;   c1 = m10 + m01;   c2 = qa[2]*qa[2]; c3 = m12 + m21; }
        else                { c0 = m10 - m01;   c1 = m20 + m02;   c2 = m21 + m12;   c3 = qa[3]*qa[3]; }
        const float denom = 2.0f * fmaxf(qa[best], 0.1f);
        float q0 = c0 / denom, q1 = c1 / denom, q2 = c2 / denom, q3 = c3 / denom;
        if (q0 < 0.0f) { q0 = -q0; q1 = -q1; q2 = -q2; q3 = -q3; }
        const float fx = intr[img * 9 + 0], fy = intr[img * 9 + 4];
        const float fovh = 2.0f * atanf((H_ * 0.5f) / fy);
        const float fovw = 2.0f * atanf((W_ * 0.5f) / fx);
        const float pg[9] = {tx * sc_, ty * sc_, tz * sc_, q0, q1, q2, q3, fovh, fovw};
        const float* ppred = posepred + img * 9;
        float s = 0.0f;
        for (int i2 = 0; i2 < 9; ++i2) {
            const float d = fabsf(ppred[i2] - pg[i2]);
            s += (d < 1.0f) ? 0.5f * d * d : d - 0.5f;
        }
        ((float*)(ws + OFF_POSE))[img] = s;
    }
}

// ---------------- fused main loss pass (packed fp32) ----------------
__global__ __launch_bounds__(256) void main_loss(
    const float* __restrict__ dp, const float* __restrict__ dg,
    const uint8_t* __restrict__ vmask, const float* __restrict__ pts_pred,
    const float* __restrict__ intr, const float* __restrict__ posegt,
    uint32_t* __restrict__ ws)
{
    const int img = blockIdx.y;
    const int t = threadIdx.x;
    __shared__ float sP[17];
    if (t == 0) {
        const float* p = posegt + img * 16;
        sP[0] = p[0]; sP[1] = p[1]; sP[2] = p[2];  sP[9]  = p[3];
        sP[3] = p[4]; sP[4] = p[5]; sP[5] = p[6];  sP[10] = p[7];
        sP[6] = p[8]; sP[7] = p[9]; sP[8] = p[10]; sP[11] = p[11];
        sP[12] = intr[img * 9 + 0]; sP[13] = intr[img * 9 + 4];
        sP[14] = intr[img * 9 + 2]; sP[15] = intr[img * 9 + 5];
        sP[16] = ((const float*)(ws + OFF_SCALE))[img];
    }
    __syncthreads();
    const float R00 = sP[0], R01 = sP[1], R02 = sP[2];
    const float R10 = sP[3], R11 = sP[4], R12 = sP[5];
    const float R20 = sP[6], R21 = sP[7], R22 = sP[8];
    const float T0 = sP[9], T1 = sP[10], T2 = sP[11];
    const float inv_fx = 1.0f / fmaxf(sP[12], EPSF);
    const float inv_fy = 1.0f / fmaxf(sP[13], EPSF);
    const float cx = sP[14], cy = sP[15];
    const float sc = sP[16];

    const size_t base = (size_t)img * HW_;
    const int pix0 = (blockIdx.x * 256 + t) * 4;
    const int i = pix0 >> 9;
    const int j0 = pix0 & 511;
    const float* dpi = dp + base;
    const float* dgi = dg + base;

    const float4 v_dp = *reinterpret_cast<const float4*>(dpi + pix0);
    const float4 v_dg = *reinterpret_cast<const float4*>(dgi + pix0);
    const uchar4 v_m  = *reinterpret_cast<const uchar4*>(vmask + base + pix0);
    const float4 ppA = *reinterpret_cast<const float4*>(pts_pred + (base + pix0) * 3);
    const float4 ppB = *reinterpret_cast<const float4*>(pts_pred + (base + pix0) * 3 + 4);
    const float4 ppC = *reinterpret_cast<const float4*>(pts_pred + (base + pix0) * 3 + 8);

    const int im = (i > 0) ? i - 1 : 0;
    const int ip = (i < H_ - 1) ? i + 1 : i;
    const int jme = (j0 > 0) ? j0 - 1 : 0;
    const int jpe = (j0 + 4 < W_) ? j0 + 4 : W_ - 1;
    const float4 dpU = *reinterpret_cast<const float4*>(dpi + im * W_ + j0);
    const float4 dpD = *reinterpret_cast<const float4*>(dpi + ip * W_ + j0);
    const float4 dgU = *reinterpret_cast<const float4*>(dgi + im * W_ + j0);
    const float4 dgD = *reinterpret_cast<const float4*>(dgi + ip * W_ + j0);
    const float dpLe = dpi[i * W_ + jme], dpRe = dpi[i * W_ + jpe];
    const float dgLe = dgi[i * W_ + jme], dgRe = dgi[i * W_ + jpe];

    const float ppv[12] = {ppA.x, ppA.y, ppA.z, ppA.w, ppB.x, ppB.y, ppB.z, ppB.w,
                           ppC.x, ppC.y, ppC.z, ppC.w};
    const float dpa[4] = {v_dp.x, v_dp.y, v_dp.z, v_dp.w};
    const float dga[4] = {v_dg.x, v_dg.y, v_dg.z, v_dg.w};
    const float dpUa[4] = {dpU.x, dpU.y, dpU.z, dpU.w};
    const float dpDa[4] = {dpD.x, dpD.y, dpD.z, dpD.w};
    const float dgUa[4] = {dgU.x, dgU.y, dgU.z, dgU.w};
    const float dgDa[4] = {dgD.x, dgD.y, dgD.z, dgD.w};
    const uint8_t ma[4] = {v_m.x, v_m.y, v_m.z, v_m.w};

    const float ay   = ((float)i - cy) * inv_fy;
    const float ay_m = ((float)(i - 1) - cy) * inv_fy;
    const float ay_p = ((float)(i + 1) - cy) * inv_fy;
    const bool row_int = (i >= 1) && (i <= H_ - 2);

    v2f dsum2 = {0, 0}, psum2 = {0, 0}, nsum2 = {0, 0}, vcnt2 = {0, 0}, ncnt2 = {0, 0};
    const v2f veps = {1e-12f, 1e-12f};
    const v2f vone = {1.0f, 1.0f};
    const v2f vmone = {-1.0f, -1.0f};

#pragma unroll
    for (int p = 0; p < 2; ++p) {
        const int e0 = 2 * p;
        const bool vm0 = ma[e0]     && finitef(dga[e0])     && (dga[e0]     > 1e-6f);
        const bool vm1 = ma[e0 + 1] && finitef(dga[e0 + 1]) && (dga[e0 + 1] > 1e-6f);
        const int ja = j0 + e0, jb = j0 + e0 + 1;
        const bool nm0 = vm0 && row_int && (ja >= 1) && (ja <= W_ - 2);
        const bool nm1 = vm1 && row_int && (jb >= 1) && (jb <= W_ - 2);
        v2f mk; mk.x = vm0 ? 1.0f : 0.0f; mk.y = vm1 ? 1.0f : 0.0f;
        v2f nk; nk.x = nm0 ? 1.0f : 0.0f; nk.y = nm1 ? 1.0f : 0.0f;
        vcnt2 += mk; ncnt2 += nk;

        const v2f jv = {(float)ja, (float)jb};
        const v2f dgv = {dga[e0], dga[e0 + 1]};
        const v2f dpv = {dpa[e0], dpa[e0 + 1]};
        const v2f dal = dgv * sc;
        dsum2 += vsel(vm0, vm1, __builtin_elementwise_abs(dpv - dal));

        const v2f ax = (jv - cx) * inv_fx;
        const v2f cxx = ax * dal;
        const v2f cyy = ay * dal;
        const v2f wx = R00 * cxx + R01 * cyy + R02 * dal + T0;
        const v2f wy = R10 * cxx + R11 * cyy + R12 * dal + T1;
        const v2f wz = R20 * cxx + R21 * cyy + R22 * dal + T2;
        const v2f px = {ppv[3 * e0],     ppv[3 * e0 + 3]};
        const v2f py = {ppv[3 * e0 + 1], ppv[3 * e0 + 4]};
        const v2f pz = {ppv[3 * e0 + 2], ppv[3 * e0 + 5]};
        psum2 += vsel(vm0, vm1,
                      __builtin_elementwise_abs(px - wx) +
                      __builtin_elementwise_abs(py - wy) +
                      __builtin_elementwise_abs(pz - wz));

        // neighbors
        const v2f pdL = (p == 0) ? v2f{dpLe, dpa[0]} : v2f{dpa[1], dpa[2]};
        const v2f pdR = (p == 0) ? v2f{dpa[1], dpa[2]} : v2f{dpa[3], dpRe};
        const v2f gdL = (p == 0) ? v2f{dgLe, dga[0]} : v2f{dga[1], dga[2]};
        const v2f gdR = (p == 0) ? v2f{dga[1], dga[2]} : v2f{dga[3], dgRe};
        const v2f pdU = {dpUa[e0], dpUa[e0 + 1]};
        const v2f pdD = {dpDa[e0], dpDa[e0 + 1]};
        const v2f gdU = {dgUa[e0], dgUa[e0 + 1]};
        const v2f gdD = {dgDa[e0], dgDa[e0 + 1]};
        const v2f ax_m = (jv - (1.0f + cx)) * inv_fx;
        const v2f ax_p = (jv + (1.0f - cx)) * inv_fx;

        v2f cpx, cpy, cpz, cgx, cgy, cgz;
        {
            const v2f dRL = pdR - pdL, dDU = pdD - pdU;
            const v2f fxx = ax_p * pdR - ax_m * pdL;
            const v2f fxy = ay * dRL;
            const v2f fyx = ax * dDU;
            const v2f fyy = ay_p * pdD - ay_m * pdU;
            cpx = fyy * dRL - dDU * fxy;
            cpy = dDU * fxx - fyx * dRL;
            cpz = fyx * fxy - fyy * fxx;
        }
        {
            const v2f dRL = gdR - gdL, dDU = gdD - gdU;
            const v2f fxx = ax_p * gdR - ax_m * gdL;
            const v2f fxy = ay * dRL;
            const v2f fyx = ax * dDU;
            const v2f fyy = ay_p * gdD - ay_m * gdU;
            cgx = fyy * dRL - dDU * fxy;
            cgy = dDU * fxx - fyx * dRL;
            cgz = fyx * fxy - fyy * fxx;
        }
        const v2f np2 = cpx * cpx + cpy * cpy + cpz * cpz;
        const v2f ng2 = cgx * cgx + cgy * cgy + cgz * cgz;
        const v2f dpg = cpx * cgx + cpy * cgy + cpz * cgz;
        const v2f den = __builtin_elementwise_max(np2, veps) *
                        __builtin_elementwise_max(ng2, veps);
        v2f r; r.x = __builtin_amdgcn_rsqf(den.x); r.y = __builtin_amdgcn_rsqf(den.y);
        v2f cosv = dpg * r;
        cosv = __builtin_elementwise_min(__builtin_elementwise_max(cosv, vmone), vone);
        nsum2 += vsel(nm0, nm1, vone - cosv);
    }

    float vals[5] = {vcnt2.x + vcnt2.y, dsum2.x + dsum2.y, psum2.x + psum2.y,
                     nsum2.x + nsum2.y, ncnt2.x + ncnt2.y};
    __shared__ float red[4][5];
    const int wave = t >> 6, lane = t & 63;
#pragma unroll
    for (int q = 0; q < 5; ++q) {
        float v = vals[q];
        for (int o = 32; o > 0; o >>= 1) v += __shfl_down(v, o);
        if (lane == 0) red[wave][q] = v;
    }
    __syncthreads();
    if (t == 0) {
        const int slot = blockIdx.y * gridDim.x + blockIdx.x;
        float* part = (float*)(ws + OFF_PART) + slot * 5;
#pragma unroll
        for (int q = 0; q < 5; ++q)
            part[q] = red[0][q] + red[1][q] + red[2][q] + red[3][q];
    }
}

// ---------------- finalize ----------------
__global__ __launch_bounds__(256) void finalize_k(const uint32_t* __restrict__ ws,
                                                  float* __restrict__ out)
{
    const float* part = (const float*)(ws + OFF_PART);
    const int t = threadIdx.x;
    double s[5] = {0, 0, 0, 0, 0};
    for (int slot = t; slot < NPARTS; slot += 256) {
#pragma unroll
        for (int q = 0; q < 5; ++q) s[q] += (double)part[slot * 5 + q];
    }
    __shared__ double red[4][5];
    const int wave = t >> 6, lane = t & 63;
#pragma unroll
    for (int q = 0; q < 5; ++q) {
        double v = s[q];
        for (int o = 32; o > 0; o >>= 1) v += __shfl_down(v, o);
        if (lane == 0) red[wave][q] = v;
    }
    __syncthreads();
    if (t == 0) {
        double tot[5];
#pragma unroll
        for (int q = 0; q < 5; ++q)
            tot[q] = red[0][q] + red[1][q] + red[2][q] + red[3][q];
        const float* pose = (const float*)(ws + OFF_POSE);
        double ps = 0.0;
        for (int i2 = 0; i2 < NIMG; ++i2) ps += (double)pose[i2];
        const double vmc = tot[0];
        const double depth_loss  = tot[1] / fmax(vmc, 1.0);
        const double points_loss = tot[2] / fmax(3.0 * vmc, 1.0);
        const double normal_loss = tot[3] / fmax(tot[4], 1.0);
        const double pose_loss   = ps / 288.0;
        out[0] = (float)(pose_loss + depth_loss + points_loss + 0.1 * normal_loss);
    }
}

extern "C" void kernel_launch(void* const* d_in, const int* in_sizes, int n_in,
                              void* d_out, int out_size, void* d_ws, size_t ws_size,
                              hipStream_t stream)
{
    const float*   dp       = (const float*)d_in[0];
    const float*   pts_pred = (const float*)d_in[1];
    const float*   posepred = (const float*)d_in[2];
    const float*   dg       = (const float*)d_in[3];
    const float*   intr     = (const float*)d_in[4];
    const float*   posegt   = (const float*)d_in[5];
    const uint8_t* vmask    = (const uint8_t*)d_in[6];
    float* out = (float*)d_out;
    uint32_t* ws = (uint32_t*)d_ws;

    const bool use_keys = ws_size >= (size_t)WS_KEYS_NEED;
    uint32_t* keys = ws + OFF_KEYS;   // only touched if use_keys

    const dim3 hgrid(HBLK, NIMG);
    hist0_k<<<hgrid, HTHR, 0, stream>>>(dp, dg, vmask, keys, ws, use_keys ? 1 : 0);
    if (use_keys) {
        histp_k<1, true><<<hgrid, HTHR, 0, stream>>>(dp, dg, vmask, keys, ws);
        histp_k<2, true><<<hgrid, HTHR, 0, stream>>>(dp, dg, vmask, keys, ws);
    } else {
        histp_k<1, false><<<hgrid, HTHR, 0, stream>>>(dp, dg, vmask, keys, ws);
        histp_k<2, false><<<hgrid, HTHR, 0, stream>>>(dp, dg, vmask, keys, ws);
    }
    sel0_k<<<NIMG, 256, 0, stream>>>(ws, intr, posegt, posepred);
    main_loss<<<dim3(192, NIMG), 256, 0, stream>>>(dp, dg, vmask, pts_pred, intr, posegt, ws);
    finalize_k<<<1, 256, 0, stream>>>(ws, out);
}